// Round 1
// baseline (5298.971 us; speedup 1.0000x reference)
//
#include <hip/hip_runtime.h>

#define IND 14
#define HIDD 64

__global__ void build_h0(const float* __restrict__ x, const float* __restrict__ pos,
                         float* __restrict__ h0, int N) {
    int tid = blockIdx.x * blockDim.x + threadIdx.x;
    int total = N * IND;
    if (tid >= total) return;
    int n = tid / IND, d = tid - n * IND;
    h0[tid] = (d < 11) ? x[n * 11 + d] : pos[n * 3 + (d - 11)];
}

__global__ void scatter1(const int* __restrict__ ei, const float* __restrict__ h0,
                         float* __restrict__ agg1, float* __restrict__ deg, int E) {
    int e = blockIdx.x * blockDim.x + threadIdx.x;
    if (e >= E) return;
    int src = ei[e], dst = ei[E + e];
    const float* hr = h0 + (size_t)src * IND;
    float* ar = agg1 + (size_t)dst * IND;
#pragma unroll
    for (int d = 0; d < IND; ++d) atomicAdd(ar + d, hr[d]);
    atomicAdd(deg + dst, 1.0f);
}

__global__ void layer1(const float* __restrict__ h0, const float* __restrict__ agg1,
                       const float* __restrict__ deg,
                       const float* __restrict__ W_l, const float* __restrict__ W_r,
                       const float* __restrict__ b, float* __restrict__ h1, int N) {
    int node = blockIdx.x * 4 + (threadIdx.x >> 6);
    int t = threadIdx.x & 63;
    if (node >= N) return;
    float invd = 1.0f / fmaxf(deg[node], 1.0f);
    float acc = b[t];
    const float* ar = agg1 + (size_t)node * IND;
    const float* hr = h0 + (size_t)node * IND;
#pragma unroll
    for (int k = 0; k < IND; ++k)
        acc += ar[k] * invd * W_l[k * HIDD + t] + hr[k] * W_r[k * HIDD + t];
    h1[(size_t)node * HIDD + t] = fmaxf(acc, 0.0f);
}

// 16 threads per edge, each does a float4 gather + 4 atomic adds
__global__ void scatter2(const int* __restrict__ ei, const float* __restrict__ h1,
                         float* __restrict__ agg2, int E) {
    long tid = (long)blockIdx.x * blockDim.x + threadIdx.x;
    long total = (long)E * 16;
    if (tid >= total) return;
    int e = (int)(tid >> 4);
    int q = (int)(tid & 15);
    int src = ei[e], dst = ei[E + e];
    const float4 v = *(const float4*)(h1 + (size_t)src * HIDD + q * 4);
    float* a = agg2 + (size_t)dst * HIDD + q * 4;
    atomicAdd(a + 0, v.x);
    atomicAdd(a + 1, v.y);
    atomicAdd(a + 2, v.z);
    atomicAdd(a + 3, v.w);
}

__global__ __launch_bounds__(256) void layer2(
        const float* __restrict__ h1, const float* __restrict__ agg2,
        const float* __restrict__ deg,
        const float* __restrict__ W_l, const float* __restrict__ W_r,
        const float* __restrict__ b, float* __restrict__ h2, int N) {
    __shared__ float sWl[HIDD * HIDD];
    __shared__ float sWr[HIDD * HIDD];
    for (int i = threadIdx.x; i < HIDD * HIDD; i += 256) {
        sWl[i] = W_l[i];
        sWr[i] = W_r[i];
    }
    __syncthreads();
    int node = blockIdx.x * 4 + (threadIdx.x >> 6);
    int t = threadIdx.x & 63;
    if (node >= N) return;
    float invd = 1.0f / fmaxf(deg[node], 1.0f);
    float acc = b[t];
    const float* ar = agg2 + (size_t)node * HIDD;
    const float* hr = h1 + (size_t)node * HIDD;
#pragma unroll 8
    for (int k = 0; k < HIDD; ++k)
        acc += ar[k] * invd * sWl[k * HIDD + t] + hr[k] * sWr[k * HIDD + t];
    h2[(size_t)node * HIDD + t] = fmaxf(acc, 0.0f);
}

__global__ void pool_k(const float* __restrict__ h2, const int* __restrict__ batch,
                       float* __restrict__ pooled, float* __restrict__ cnt, int N) {
    long tid = (long)blockIdx.x * blockDim.x + threadIdx.x;
    long total = (long)N * HIDD;
    if (tid >= total) return;
    int node = (int)(tid >> 6);
    int d = (int)(tid & 63);
    int g = batch[node];
    atomicAdd(pooled + (size_t)g * HIDD + d, h2[(size_t)node * HIDD + d]);
    if (d == 0) atomicAdd(cnt + g, 1.0f);
}

__global__ void final_k(const float* __restrict__ pooled, const float* __restrict__ cnt,
                        const float* __restrict__ W, const float* __restrict__ bl,
                        float* __restrict__ out, int G) {
    int g = blockIdx.x;
    if (g >= G) return;
    int t = threadIdx.x;
    float invc = 1.0f / fmaxf(cnt[g], 1.0f);
    float v = pooled[(size_t)g * HIDD + t] * invc * W[t];
#pragma unroll
    for (int o = 32; o > 0; o >>= 1) v += __shfl_down(v, o, 64);
    if (t == 0) out[g] = v + bl[0];
}

extern "C" void kernel_launch(void* const* d_in, const int* in_sizes, int n_in,
                              void* d_out, int out_size, void* d_ws, size_t ws_size,
                              hipStream_t stream) {
    const float* x   = (const float*)d_in[0];
    const float* pos = (const float*)d_in[1];
    const int* ei    = (const int*)d_in[2];
    const int* batch = (const int*)d_in[3];
    const float* W1l = (const float*)d_in[4];
    const float* W1r = (const float*)d_in[5];
    const float* b1  = (const float*)d_in[6];
    const float* W2l = (const float*)d_in[7];
    const float* W2r = (const float*)d_in[8];
    const float* b2  = (const float*)d_in[9];
    const float* Wl  = (const float*)d_in[10];
    const float* bl  = (const float*)d_in[11];
    float* out = (float*)d_out;

    int N = in_sizes[3];
    int E = in_sizes[2] / 2;
    int G = out_size;

    float* ws = (float*)d_ws;
    size_t off = 0;
    float* h0 = ws + off;     off += (size_t)N * IND;
    float* h1 = ws + off;     off += (size_t)N * HIDD;
    float* h2 = ws + off;     off += (size_t)N * HIDD;
    // contiguous zero region: agg1, deg, agg2, pooled, cnt
    float* agg1 = ws + off;   off += (size_t)N * IND;
    float* deg = ws + off;    off += (size_t)N;
    float* agg2 = ws + off;   off += (size_t)N * HIDD;
    float* pooled = ws + off; off += (size_t)G * HIDD;
    float* cnt = ws + off;    off += (size_t)G;
    size_t zero_bytes = ((size_t)N * IND + N + (size_t)N * HIDD +
                         (size_t)G * HIDD + G) * sizeof(float);
    hipMemsetAsync(agg1, 0, zero_bytes, stream);

    int blk = 256;
    build_h0<<<((size_t)N * IND + blk - 1) / blk, blk, 0, stream>>>(x, pos, h0, N);
    scatter1<<<(E + blk - 1) / blk, blk, 0, stream>>>(ei, h0, agg1, deg, E);
    layer1<<<(N + 3) / 4, blk, 0, stream>>>(h0, agg1, deg, W1l, W1r, b1, h1, N);
    scatter2<<<((size_t)E * 16 + blk - 1) / blk, blk, 0, stream>>>(ei, h1, agg2, E);
    layer2<<<(N + 3) / 4, blk, 0, stream>>>(h1, agg2, deg, W2l, W2r, b2, h2, N);
    pool_k<<<((size_t)N * HIDD + blk - 1) / blk, blk, 0, stream>>>(h2, batch, pooled, cnt, N);
    final_k<<<G, 64, 0, stream>>>(pooled, cnt, Wl, bl, out, G);
}

// Round 3
// 1210.413 us; speedup vs baseline: 4.3778x; 4.3778x over previous
//
#include <hip/hip_runtime.h>

#define IND 14
#define HIDD 64
#define SCAN_BLK 1024

__global__ void build_h0(const float* __restrict__ x, const float* __restrict__ pos,
                         float* __restrict__ h0, int N) {
    int tid = blockIdx.x * blockDim.x + threadIdx.x;
    int total = N * IND;
    if (tid >= total) return;
    int n = tid / IND, d = tid - n * IND;
    h0[tid] = (d < 11) ? x[n * 11 + d] : pos[n * 3 + (d - 11)];
}

__global__ void hist_k(const int* __restrict__ ei, int* __restrict__ deg_i, int E) {
    int e = blockIdx.x * blockDim.x + threadIdx.x;
    if (e >= E) return;
    atomicAdd(deg_i + ei[E + e], 1);
}

__global__ __launch_bounds__(SCAN_BLK) void scan1(const int* __restrict__ deg_i,
                                                  int* __restrict__ incl,
                                                  int* __restrict__ bsum, int N) {
    __shared__ int s[SCAN_BLK];
    int i = blockIdx.x * SCAN_BLK + threadIdx.x;
    s[threadIdx.x] = (i < N) ? deg_i[i] : 0;
    __syncthreads();
    for (int off = 1; off < SCAN_BLK; off <<= 1) {
        int t = (threadIdx.x >= off) ? s[threadIdx.x - off] : 0;
        __syncthreads();
        s[threadIdx.x] += t;
        __syncthreads();
    }
    if (i < N) incl[i] = s[threadIdx.x];
    if (threadIdx.x == SCAN_BLK - 1) bsum[blockIdx.x] = s[SCAN_BLK - 1];
}

__global__ void scan2(int* __restrict__ bsum, int nb) {
    if (blockIdx.x == 0 && threadIdx.x == 0) {
        int run = 0;
        for (int b = 0; b < nb; ++b) { int v = bsum[b]; bsum[b] = run; run += v; }
    }
}

__global__ void scan3(const int* __restrict__ incl, const int* __restrict__ bsum,
                      int* __restrict__ rowptr, int N) {
    int i = blockIdx.x * blockDim.x + threadIdx.x;
    if (i >= N) return;
    rowptr[i + 1] = incl[i] + bsum[i >> 10];
    if (i == 0) rowptr[0] = 0;
}

__global__ void fill_csr(const int* __restrict__ ei, const int* __restrict__ rowptr,
                         int* __restrict__ fill, int* __restrict__ csr, int E) {
    int e = blockIdx.x * blockDim.x + threadIdx.x;
    if (e >= E) return;
    int src = ei[e], dst = ei[E + e];
    int p = atomicAdd(fill + dst, 1);
    csr[rowptr[dst] + p] = src;
}

// thread per (node, dim) with dim padded to 16; gather-mean h0 rows
__global__ void gather1(const float* __restrict__ h0, const int* __restrict__ rowptr,
                        const int* __restrict__ csr, float* __restrict__ agg1, int N) {
    long tid = (long)blockIdx.x * blockDim.x + threadIdx.x;
    int node = (int)(tid >> 4);
    int d = (int)(tid & 15);
    if (node >= N || d >= IND) return;
    int beg = rowptr[node], end = rowptr[node + 1];
    float acc = 0.0f;
    for (int e = beg; e < end; ++e) acc += h0[(size_t)csr[e] * IND + d];
    float invd = 1.0f / fmaxf((float)(end - beg), 1.0f);
    agg1[(size_t)node * IND + d] = acc * invd;
}

__global__ void layer1(const float* __restrict__ h0, const float* __restrict__ agg1,
                       const float* __restrict__ W_l, const float* __restrict__ W_r,
                       const float* __restrict__ b, float* __restrict__ h1, int N) {
    int node = blockIdx.x * 4 + (threadIdx.x >> 6);
    int t = threadIdx.x & 63;
    if (node >= N) return;
    float acc = b[t];
    const float* ar = agg1 + (size_t)node * IND;
    const float* hr = h0 + (size_t)node * IND;
#pragma unroll
    for (int k = 0; k < IND; ++k)
        acc += ar[k] * W_l[k * HIDD + t] + hr[k] * W_r[k * HIDD + t];
    h1[(size_t)node * HIDD + t] = fmaxf(acc, 0.0f);
}

// fused: wave-per-node gather-mean of h1 + 64x64 GEMMs from LDS
__global__ __launch_bounds__(256) void agg_layer2(
        const float* __restrict__ h1, const int* __restrict__ rowptr,
        const int* __restrict__ csr,
        const float* __restrict__ W_l, const float* __restrict__ W_r,
        const float* __restrict__ b, float* __restrict__ h2, int N) {
    __shared__ float sWl[HIDD * HIDD];
    __shared__ float sWr[HIDD * HIDD];
    __shared__ float sAgg[4][HIDD];
    __shared__ float sH[4][HIDD];
    for (int i = threadIdx.x; i < HIDD * HIDD; i += 256) {
        sWl[i] = W_l[i];
        sWr[i] = W_r[i];
    }
    int w = threadIdx.x >> 6;
    int t = threadIdx.x & 63;
    int node = blockIdx.x * 4 + w;
    if (node < N) {
        int beg = rowptr[node], end = rowptr[node + 1];
        float acc = 0.0f;
        for (int e = beg; e < end; ++e) acc += h1[(size_t)csr[e] * HIDD + t];
        float invd = 1.0f / fmaxf((float)(end - beg), 1.0f);
        sAgg[w][t] = acc * invd;
        sH[w][t] = h1[(size_t)node * HIDD + t];
    }
    __syncthreads();
    if (node >= N) return;
    float acc = b[t];
#pragma unroll 8
    for (int k = 0; k < HIDD; ++k)
        acc += sAgg[w][k] * sWl[k * HIDD + t] + sH[w][k] * sWr[k * HIDD + t];
    h2[(size_t)node * HIDD + t] = fmaxf(acc, 0.0f);
}

__global__ void pool_k(const float* __restrict__ h2, const int* __restrict__ batch,
                       float* __restrict__ pooled, float* __restrict__ cnt, int N) {
    long tid = (long)blockIdx.x * blockDim.x + threadIdx.x;
    long total = (long)N * HIDD;
    if (tid >= total) return;
    int node = (int)(tid >> 6);
    int d = (int)(tid & 63);
    int g = batch[node];
    atomicAdd(pooled + (size_t)g * HIDD + d, h2[(size_t)node * HIDD + d]);
    if (d == 0) atomicAdd(cnt + g, 1.0f);
}

__global__ void final_k(const float* __restrict__ pooled, const float* __restrict__ cnt,
                        const float* __restrict__ W, const float* __restrict__ bl,
                        float* __restrict__ out, int G) {
    int g = blockIdx.x;
    if (g >= G) return;
    int t = threadIdx.x;
    float invc = 1.0f / fmaxf(cnt[g], 1.0f);
    float v = pooled[(size_t)g * HIDD + t] * invc * W[t];
#pragma unroll
    for (int o = 32; o > 0; o >>= 1) v += __shfl_down(v, o, 64);
    if (t == 0) out[g] = v + bl[0];
}

extern "C" void kernel_launch(void* const* d_in, const int* in_sizes, int n_in,
                              void* d_out, int out_size, void* d_ws, size_t ws_size,
                              hipStream_t stream) {
    const float* x   = (const float*)d_in[0];
    const float* pos = (const float*)d_in[1];
    const int* ei    = (const int*)d_in[2];
    const int* batch = (const int*)d_in[3];
    const float* W1l = (const float*)d_in[4];
    const float* W1r = (const float*)d_in[5];
    const float* b1  = (const float*)d_in[6];
    const float* W2l = (const float*)d_in[7];
    const float* W2r = (const float*)d_in[8];
    const float* b2  = (const float*)d_in[9];
    const float* Wl  = (const float*)d_in[10];
    const float* bl  = (const float*)d_in[11];
    float* out = (float*)d_out;

    int N = in_sizes[3];
    int E = in_sizes[2] / 2;
    int G = out_size;
    int nb = (N + SCAN_BLK - 1) / SCAN_BLK;

    char* ws = (char*)d_ws;
    size_t off = 0;
    // ---- zero region (contiguous) ----
    int* deg_i = (int*)(ws + off);   off += (size_t)N * 4;
    int* fill  = (int*)(ws + off);   off += (size_t)N * 4;
    int* bsum  = (int*)(ws + off);   off += (size_t)(nb + 1) * 4;
    float* cnt = (float*)(ws + off); off += (size_t)G * 4;
    float* pooled = (float*)(ws + off); off += (size_t)G * HIDD * 4;
    size_t zero_bytes = off;
    // ---- rest ----
    int* incl   = (int*)(ws + off);  off += (size_t)N * 4;
    int* rowptr = (int*)(ws + off);  off += (size_t)(N + 1) * 4;
    int* csr    = (int*)(ws + off);  off += (size_t)E * 4;
    float* h0   = (float*)(ws + off); off += (size_t)N * IND * 4;
    float* h1   = (float*)(ws + off); off += (size_t)N * HIDD * 4;
    float* h2   = (float*)(ws + off); off += (size_t)N * HIDD * 4;
    float* agg1 = (float*)(ws + off); off += (size_t)N * IND * 4;

    hipMemsetAsync(d_ws, 0, zero_bytes, stream);

    int blk = 256;
    build_h0<<<((size_t)N * IND + blk - 1) / blk, blk, 0, stream>>>(x, pos, h0, N);
    hist_k<<<(E + blk - 1) / blk, blk, 0, stream>>>(ei, deg_i, E);
    scan1<<<nb, SCAN_BLK, 0, stream>>>(deg_i, incl, bsum, N);
    scan2<<<1, 64, 0, stream>>>(bsum, nb);
    scan3<<<(N + blk - 1) / blk, blk, 0, stream>>>(incl, bsum, rowptr, N);
    fill_csr<<<(E + blk - 1) / blk, blk, 0, stream>>>(ei, rowptr, fill, csr, E);
    gather1<<<((size_t)N * 16 + blk - 1) / blk, blk, 0, stream>>>(h0, rowptr, csr, agg1, N);
    layer1<<<(N + 3) / 4, blk, 0, stream>>>(h0, agg1, W1l, W1r, b1, h1, N);
    agg_layer2<<<(N + 3) / 4, blk, 0, stream>>>(h1, rowptr, csr, W2l, W2r, b2, h2, N);
    pool_k<<<((size_t)N * HIDD + blk - 1) / blk, blk, 0, stream>>>(h2, batch, pooled, cnt, N);
    final_k<<<G, 64, 0, stream>>>(pooled, cnt, Wl, bl, out, G);
}

// Round 4
// 668.682 us; speedup vs baseline: 7.9245x; 1.8101x over previous
//
#include <hip/hip_runtime.h>

#define IND 14
#define INDP 16
#define HIDD 64
#define SCAN_BLK 1024

__global__ void build_h0p(const float* __restrict__ x, const float* __restrict__ pos,
                          float* __restrict__ h0p, int N) {
    int tid = blockIdx.x * blockDim.x + threadIdx.x;
    int total = N * INDP;
    if (tid >= total) return;
    int n = tid >> 4, d = tid & 15;
    float v = 0.0f;
    if (d < 11) v = x[n * 11 + d];
    else if (d < 14) v = pos[n * 3 + (d - 11)];
    h0p[tid] = v;
}

__global__ void hist_k(const int* __restrict__ ei, int* __restrict__ deg_i, int E) {
    int e = blockIdx.x * blockDim.x + threadIdx.x;
    if (e >= E) return;
    atomicAdd(deg_i + ei[E + e], 1);
}

__global__ __launch_bounds__(SCAN_BLK) void scan1(const int* __restrict__ deg_i,
                                                  int* __restrict__ incl,
                                                  int* __restrict__ bsum, int N) {
    __shared__ int s[SCAN_BLK];
    int i = blockIdx.x * SCAN_BLK + threadIdx.x;
    s[threadIdx.x] = (i < N) ? deg_i[i] : 0;
    __syncthreads();
    for (int off = 1; off < SCAN_BLK; off <<= 1) {
        int t = (threadIdx.x >= off) ? s[threadIdx.x - off] : 0;
        __syncthreads();
        s[threadIdx.x] += t;
        __syncthreads();
    }
    if (i < N) incl[i] = s[threadIdx.x];
    if (threadIdx.x == SCAN_BLK - 1) bsum[blockIdx.x] = s[SCAN_BLK - 1];
}

// LDS scan over block sums (nb <= 1024)
__global__ __launch_bounds__(SCAN_BLK) void scan2(int* __restrict__ bsum, int nb) {
    __shared__ int s[SCAN_BLK];
    int i = threadIdx.x;
    s[i] = (i < nb) ? bsum[i] : 0;
    __syncthreads();
    for (int off = 1; off < SCAN_BLK; off <<= 1) {
        int t = (i >= off) ? s[i - off] : 0;
        __syncthreads();
        s[i] += t;
        __syncthreads();
    }
    if (i < nb) bsum[i] = (i == 0) ? 0 : s[i - 1];
}

__global__ void scan3(const int* __restrict__ incl, const int* __restrict__ bsum,
                      int* __restrict__ rowptr, int N) {
    int i = blockIdx.x * blockDim.x + threadIdx.x;
    if (i >= N) return;
    rowptr[i + 1] = incl[i] + bsum[i >> 10];
    if (i == 0) rowptr[0] = 0;
}

__global__ void fill_csr(const int* __restrict__ ei, const int* __restrict__ rowptr,
                         int* __restrict__ fill, int* __restrict__ csr, int E) {
    int e = blockIdx.x * blockDim.x + threadIdx.x;
    if (e >= E) return;
    int src = ei[e], dst = ei[E + e];
    int p = atomicAdd(fill + dst, 1);
    csr[rowptr[dst] + p] = src;
}

// fused gather-mean(h0p) + layer1 GEMM; wave per node, 8 nodes/block
__global__ __launch_bounds__(512) void agg_layer1(
        const float* __restrict__ h0p, const int* __restrict__ rowptr,
        const int* __restrict__ csr,
        const float* __restrict__ W_l, const float* __restrict__ W_r,
        const float* __restrict__ b, float* __restrict__ h1, int N) {
    __shared__ float sWl[IND * HIDD];
    __shared__ float sWr[IND * HIDD];
    __shared__ float sA[8][INDP];
    __shared__ float sS[8][INDP];
    for (int i = threadIdx.x; i < IND * HIDD; i += 512) {
        sWl[i] = W_l[i];
        sWr[i] = W_r[i];
    }
    int w = threadIdx.x >> 6, t = threadIdx.x & 63;
    int node = blockIdx.x * 8 + w;
    if (node < N) {
        int beg = rowptr[node], end = rowptr[node + 1];
        int s = t >> 2, q = t & 3;  // 16 neighbor slots x 4-float quads
        float4 acc = make_float4(0.f, 0.f, 0.f, 0.f);
        for (int e = beg + s; e < end; e += 16) {
            int idx = csr[e];
            const float4 v = *(const float4*)(h0p + (size_t)idx * INDP + q * 4);
            acc.x += v.x; acc.y += v.y; acc.z += v.z; acc.w += v.w;
        }
#pragma unroll
        for (int m = 4; m < 64; m <<= 1) {
            acc.x += __shfl_xor(acc.x, m, 64);
            acc.y += __shfl_xor(acc.y, m, 64);
            acc.z += __shfl_xor(acc.z, m, 64);
            acc.w += __shfl_xor(acc.w, m, 64);
        }
        float invd = 1.0f / fmaxf((float)(end - beg), 1.0f);
        if (t < 4)
            *(float4*)(&sA[w][t * 4]) =
                make_float4(acc.x * invd, acc.y * invd, acc.z * invd, acc.w * invd);
        if (t < INDP) sS[w][t] = h0p[(size_t)node * INDP + t];
    }
    __syncthreads();
    if (node >= N) return;
    float acc = b[t];
#pragma unroll
    for (int k = 0; k < IND; ++k)
        acc += sA[w][k] * sWl[k * HIDD + t] + sS[w][k] * sWr[k * HIDD + t];
    h1[(size_t)node * HIDD + t] = fmaxf(acc, 0.0f);
}

// fused gather-mean(h1) + layer2 GEMM + pooled atomic; wave per node, 8 nodes/block
__global__ __launch_bounds__(512) void agg_layer2(
        const float* __restrict__ h1, const int* __restrict__ rowptr,
        const int* __restrict__ csr, const int* __restrict__ batch,
        const float* __restrict__ W_l, const float* __restrict__ W_r,
        const float* __restrict__ b,
        float* __restrict__ pooled, float* __restrict__ cnt, int N) {
    __shared__ float sWl[HIDD * HIDD];
    __shared__ float sWr[HIDD * HIDD];
    __shared__ float sA[8][HIDD];
    __shared__ float sS[8][HIDD];
    for (int i = threadIdx.x; i < HIDD * HIDD; i += 512) {
        sWl[i] = W_l[i];
        sWr[i] = W_r[i];
    }
    int w = threadIdx.x >> 6, t = threadIdx.x & 63;
    int node = blockIdx.x * 8 + w;
    if (node < N) {
        int beg = rowptr[node], end = rowptr[node + 1];
        int s = t >> 4, q = t & 15;  // 4 neighbor slots x 16-float4 quads
        float4 a0 = make_float4(0.f, 0.f, 0.f, 0.f);
        float4 a1 = make_float4(0.f, 0.f, 0.f, 0.f);
        int e = beg + s;
        // 2x unroll: 8 independent row-load chains in flight per wave
        for (; e + 4 < end; e += 8) {
            int i0 = csr[e];
            int i1 = csr[e + 4];
            const float4 v0 = *(const float4*)(h1 + (size_t)i0 * HIDD + q * 4);
            const float4 v1 = *(const float4*)(h1 + (size_t)i1 * HIDD + q * 4);
            a0.x += v0.x; a0.y += v0.y; a0.z += v0.z; a0.w += v0.w;
            a1.x += v1.x; a1.y += v1.y; a1.z += v1.z; a1.w += v1.w;
        }
        if (e < end) {
            int i0 = csr[e];
            const float4 v0 = *(const float4*)(h1 + (size_t)i0 * HIDD + q * 4);
            a0.x += v0.x; a0.y += v0.y; a0.z += v0.z; a0.w += v0.w;
        }
        a0.x += a1.x; a0.y += a1.y; a0.z += a1.z; a0.w += a1.w;
#pragma unroll
        for (int m = 16; m < 64; m <<= 1) {
            a0.x += __shfl_xor(a0.x, m, 64);
            a0.y += __shfl_xor(a0.y, m, 64);
            a0.z += __shfl_xor(a0.z, m, 64);
            a0.w += __shfl_xor(a0.w, m, 64);
        }
        float invd = 1.0f / fmaxf((float)(end - beg), 1.0f);
        if (t < 16)
            *(float4*)(&sA[w][t * 4]) =
                make_float4(a0.x * invd, a0.y * invd, a0.z * invd, a0.w * invd);
        sS[w][t] = h1[(size_t)node * HIDD + t];
    }
    __syncthreads();
    if (node >= N) return;
    float acc = b[t];
#pragma unroll 8
    for (int k = 0; k < HIDD; ++k)
        acc += sA[w][k] * sWl[k * HIDD + t] + sS[w][k] * sWr[k * HIDD + t];
    float val = fmaxf(acc, 0.0f);
    int g = batch[node];
    atomicAdd(pooled + (size_t)g * HIDD + t, val);
    if (t == 0) atomicAdd(cnt + g, 1.0f);
}

__global__ void final_k(const float* __restrict__ pooled, const float* __restrict__ cnt,
                        const float* __restrict__ W, const float* __restrict__ bl,
                        float* __restrict__ out, int G) {
    int g = blockIdx.x;
    if (g >= G) return;
    int t = threadIdx.x;
    float invc = 1.0f / fmaxf(cnt[g], 1.0f);
    float v = pooled[(size_t)g * HIDD + t] * invc * W[t];
#pragma unroll
    for (int o = 32; o > 0; o >>= 1) v += __shfl_down(v, o, 64);
    if (t == 0) out[g] = v + bl[0];
}

extern "C" void kernel_launch(void* const* d_in, const int* in_sizes, int n_in,
                              void* d_out, int out_size, void* d_ws, size_t ws_size,
                              hipStream_t stream) {
    const float* x   = (const float*)d_in[0];
    const float* pos = (const float*)d_in[1];
    const int* ei    = (const int*)d_in[2];
    const int* batch = (const int*)d_in[3];
    const float* W1l = (const float*)d_in[4];
    const float* W1r = (const float*)d_in[5];
    const float* b1  = (const float*)d_in[6];
    const float* W2l = (const float*)d_in[7];
    const float* W2r = (const float*)d_in[8];
    const float* b2  = (const float*)d_in[9];
    const float* Wl  = (const float*)d_in[10];
    const float* bl  = (const float*)d_in[11];
    float* out = (float*)d_out;

    int N = in_sizes[3];
    int E = in_sizes[2] / 2;
    int G = out_size;
    int nb = (N + SCAN_BLK - 1) / SCAN_BLK;

    char* ws = (char*)d_ws;
    size_t off = 0;
    // ---- zero region (contiguous, memset below) ----
    int* deg_i = (int*)(ws + off);      off += (size_t)N * 4;
    int* fill  = (int*)(ws + off);      off += (size_t)N * 4;
    int* bsum  = (int*)(ws + off);      off += (size_t)(nb + 1) * 4;
    float* cnt = (float*)(ws + off);    off += (size_t)G * 4;
    float* pooled = (float*)(ws + off); off += (size_t)G * HIDD * 4;
    size_t zero_bytes = off;
    // ---- rest (align big float4 buffers to 256B) ----
    int* incl   = (int*)(ws + off);     off += (size_t)N * 4;
    int* rowptr = (int*)(ws + off);     off += (size_t)(N + 1) * 4;
    int* csr    = (int*)(ws + off);     off += (size_t)E * 4;
    off = (off + 255) & ~(size_t)255;
    float* h0p  = (float*)(ws + off);   off += (size_t)N * INDP * 4;
    off = (off + 255) & ~(size_t)255;
    float* h1   = (float*)(ws + off);   off += (size_t)N * HIDD * 4;

    hipMemsetAsync(d_ws, 0, zero_bytes, stream);

    int blk = 256;
    build_h0p<<<((size_t)N * INDP + blk - 1) / blk, blk, 0, stream>>>(x, pos, h0p, N);
    hist_k<<<(E + blk - 1) / blk, blk, 0, stream>>>(ei, deg_i, E);
    scan1<<<nb, SCAN_BLK, 0, stream>>>(deg_i, incl, bsum, N);
    scan2<<<1, SCAN_BLK, 0, stream>>>(bsum, nb);
    scan3<<<(N + blk - 1) / blk, blk, 0, stream>>>(incl, bsum, rowptr, N);
    fill_csr<<<(E + blk - 1) / blk, blk, 0, stream>>>(ei, rowptr, fill, csr, E);
    agg_layer1<<<(N + 7) / 8, 512, 0, stream>>>(h0p, rowptr, csr, W1l, W1r, b1, h1, N);
    agg_layer2<<<(N + 7) / 8, 512, 0, stream>>>(h1, rowptr, csr, batch, W2l, W2r, b2,
                                                pooled, cnt, N);
    final_k<<<G, 64, 0, stream>>>(pooled, cnt, Wl, bl, out, G);
}

// Round 5
// 390.508 us; speedup vs baseline: 13.5694x; 1.7123x over previous
//
#include <hip/hip_runtime.h>

#define IND 14
#define INDP 16
#define HIDD 64
#define RB 512          // nodes per bucket (shift 9)
#define NB_MAX 256
#define BH_BLOCKS 512   // blocks for bhist/bscatter (must stay 512: bscan1 does 8x64)

__global__ void build_h0p(const float* __restrict__ x, const float* __restrict__ pos,
                          float* __restrict__ h0p, int N) {
    int tid = blockIdx.x * blockDim.x + threadIdx.x;
    int total = N * INDP;
    if (tid >= total) return;
    int n = tid >> 4, d = tid & 15;
    float v = 0.0f;
    if (d < 11) v = x[n * 11 + d];
    else if (d < 14) v = pos[n * 3 + (d - 11)];
    h0p[tid] = v;
}

// A: per-block bucket histogram (LDS atomics only)
__global__ __launch_bounds__(256) void bhist(const int* __restrict__ ei,
                                             int* __restrict__ gcount,
                                             int E, int NB, int chunk) {
    __shared__ int cntS[NB_MAX];
    cntS[threadIdx.x] = 0;
    if (threadIdx.x + 128 < NB_MAX) {}  // (256 threads cover NB_MAX=256)
    __syncthreads();
    int start = blockIdx.x * chunk;
    int end = min(start + chunk, E);
    for (int e = start + threadIdx.x; e < end; e += 256)
        atomicAdd(&cntS[ei[E + e] >> 9], 1);
    __syncthreads();
    if (threadIdx.x < NB)
        gcount[(size_t)threadIdx.x * BH_BLOCKS + blockIdx.x] = cntS[threadIdx.x];
}

// B1: wave per bucket — exclusive scan of 512 per-block counts
__global__ __launch_bounds__(256) void bscan1(const int* __restrict__ gcount,
                                              int* __restrict__ gbase,
                                              int* __restrict__ btot, int NB) {
    int wave = blockIdx.x * 4 + (threadIdx.x >> 6);
    int lane = threadIdx.x & 63;
    if (wave >= NB) return;
    const int* src = gcount + (size_t)wave * BH_BLOCKS;
    int* dstp = gbase + (size_t)wave * BH_BLOCKS;
    int run = 0;
#pragma unroll
    for (int r = 0; r < 8; ++r) {
        int val = src[r * 64 + lane];
        int inc = val;
#pragma unroll
        for (int off = 1; off < 64; off <<= 1) {
            int tv = __shfl_up(inc, off, 64);
            if (lane >= off) inc += tv;
        }
        dstp[r * 64 + lane] = run + inc - val;
        run += __shfl(inc, 63, 64);
    }
    if (lane == 0) btot[wave] = run;
}

// B2: single wave — exclusive scan of bucket totals; also rowptr[N]=E
__global__ void bscan2(const int* __restrict__ btot, int* __restrict__ bbase,
                       int* __restrict__ rowptr, int NB, int N, int E) {
    int lane = threadIdx.x;
    int run = 0;
#pragma unroll
    for (int r = 0; r < 4; ++r) {
        int i = r * 64 + lane;
        int val = (i < NB) ? btot[i] : 0;
        int inc = val;
#pragma unroll
        for (int off = 1; off < 64; off <<= 1) {
            int tv = __shfl_up(inc, off, 64);
            if (lane >= off) inc += tv;
        }
        if (i < NB) bbase[i] = run + inc - val;
        run += __shfl(inc, 63, 64);
    }
    if (lane == 0) rowptr[N] = E;
}

// C: scatter edges into bucket-contiguous pairs via LDS cursors
__global__ __launch_bounds__(256) void bscatter(const int* __restrict__ ei,
                                                const int* __restrict__ gbase,
                                                const int* __restrict__ bbase,
                                                int2* __restrict__ pairs,
                                                int E, int NB, int chunk) {
    __shared__ int cur[NB_MAX];
    if (threadIdx.x < NB)
        cur[threadIdx.x] = bbase[threadIdx.x] +
                           gbase[(size_t)threadIdx.x * BH_BLOCKS + blockIdx.x];
    __syncthreads();
    int start = blockIdx.x * chunk;
    int end = min(start + chunk, E);
    for (int e = start + threadIdx.x; e < end; e += 256) {
        int s = ei[e], d = ei[E + e];
        int p = atomicAdd(&cur[d >> 9], 1);
        pairs[p] = make_int2(s, d);
    }
}

// D: block per bucket — LDS deg hist + scan -> rowptr + csr (contiguous window)
__global__ __launch_bounds__(1024) void csr_build(const int2* __restrict__ pairs,
                                                  const int* __restrict__ btot,
                                                  const int* __restrict__ bbase,
                                                  int* __restrict__ rowptr,
                                                  int* __restrict__ csr, int N) {
    __shared__ int s[RB];
    __shared__ int fillS[RB];
    int b = blockIdx.x;
    int cnt = btot[b], base = bbase[b];
    int t = threadIdx.x;
    if (t < RB) { s[t] = 0; fillS[t] = 0; }
    __syncthreads();
    for (int i = t; i < cnt; i += 1024)
        atomicAdd(&s[pairs[base + i].y & (RB - 1)], 1);
    __syncthreads();
    for (int off = 1; off < RB; off <<= 1) {
        int v = 0;
        if (t < RB && t >= off) v = s[t - off];
        __syncthreads();
        if (t < RB) s[t] += v;
        __syncthreads();
    }
    int node0 = b << 9;
    if (t < RB) {
        int node = node0 + t;
        if (node < N) rowptr[node] = base + (t ? s[t - 1] : 0);
    }
    __syncthreads();
    for (int i = t; i < cnt; i += 1024) {
        int2 pr = pairs[base + i];
        int local = pr.y & (RB - 1);
        int p = atomicAdd(&fillS[local], 1);
        int segbase = local ? s[local - 1] : 0;
        csr[base + segbase + p] = pr.x;
    }
}

// fused gather-mean(h0p) + layer1 GEMM; wave per node, 8 nodes/block
__global__ __launch_bounds__(512) void agg_layer1(
        const float* __restrict__ h0p, const int* __restrict__ rowptr,
        const int* __restrict__ csr,
        const float* __restrict__ W_l, const float* __restrict__ W_r,
        const float* __restrict__ b, float* __restrict__ h1, int N) {
    __shared__ float sWl[IND * HIDD];
    __shared__ float sWr[IND * HIDD];
    __shared__ float sA[8][INDP];
    __shared__ float sS[8][INDP];
    for (int i = threadIdx.x; i < IND * HIDD; i += 512) {
        sWl[i] = W_l[i];
        sWr[i] = W_r[i];
    }
    int w = threadIdx.x >> 6, t = threadIdx.x & 63;
    int node = blockIdx.x * 8 + w;
    if (node < N) {
        int beg = rowptr[node], end = rowptr[node + 1];
        int s = t >> 2, q = t & 3;
        float4 acc = make_float4(0.f, 0.f, 0.f, 0.f);
        for (int e = beg + s; e < end; e += 16) {
            int idx = csr[e];
            const float4 v = *(const float4*)(h0p + (size_t)idx * INDP + q * 4);
            acc.x += v.x; acc.y += v.y; acc.z += v.z; acc.w += v.w;
        }
#pragma unroll
        for (int m = 4; m < 64; m <<= 1) {
            acc.x += __shfl_xor(acc.x, m, 64);
            acc.y += __shfl_xor(acc.y, m, 64);
            acc.z += __shfl_xor(acc.z, m, 64);
            acc.w += __shfl_xor(acc.w, m, 64);
        }
        float invd = 1.0f / fmaxf((float)(end - beg), 1.0f);
        if (t < 4)
            *(float4*)(&sA[w][t * 4]) =
                make_float4(acc.x * invd, acc.y * invd, acc.z * invd, acc.w * invd);
        if (t < INDP) sS[w][t] = h0p[(size_t)node * INDP + t];
    }
    __syncthreads();
    if (node >= N) return;
    float acc = b[t];
#pragma unroll
    for (int k = 0; k < IND; ++k)
        acc += sA[w][k] * sWl[k * HIDD + t] + sS[w][k] * sWr[k * HIDD + t];
    h1[(size_t)node * HIDD + t] = fmaxf(acc, 0.0f);
}

// fused gather-mean(h1) + layer2 GEMM + pooled atomic; wave per node, 8 nodes/block
__global__ __launch_bounds__(512) void agg_layer2(
        const float* __restrict__ h1, const int* __restrict__ rowptr,
        const int* __restrict__ csr, const int* __restrict__ batch,
        const float* __restrict__ W_l, const float* __restrict__ W_r,
        const float* __restrict__ b,
        float* __restrict__ pooled, float* __restrict__ cnt, int N) {
    __shared__ float sWl[HIDD * HIDD];
    __shared__ float sWr[HIDD * HIDD];
    __shared__ float sA[8][HIDD];
    __shared__ float sS[8][HIDD];
    for (int i = threadIdx.x; i < HIDD * HIDD; i += 512) {
        sWl[i] = W_l[i];
        sWr[i] = W_r[i];
    }
    int w = threadIdx.x >> 6, t = threadIdx.x & 63;
    int node = blockIdx.x * 8 + w;
    if (node < N) {
        int beg = rowptr[node], end = rowptr[node + 1];
        int s = t >> 4, q = t & 15;
        float4 a0 = make_float4(0.f, 0.f, 0.f, 0.f);
        float4 a1 = make_float4(0.f, 0.f, 0.f, 0.f);
        int e = beg + s;
        for (; e + 4 < end; e += 8) {
            int i0 = csr[e];
            int i1 = csr[e + 4];
            const float4 v0 = *(const float4*)(h1 + (size_t)i0 * HIDD + q * 4);
            const float4 v1 = *(const float4*)(h1 + (size_t)i1 * HIDD + q * 4);
            a0.x += v0.x; a0.y += v0.y; a0.z += v0.z; a0.w += v0.w;
            a1.x += v1.x; a1.y += v1.y; a1.z += v1.z; a1.w += v1.w;
        }
        if (e < end) {
            int i0 = csr[e];
            const float4 v0 = *(const float4*)(h1 + (size_t)i0 * HIDD + q * 4);
            a0.x += v0.x; a0.y += v0.y; a0.z += v0.z; a0.w += v0.w;
        }
        a0.x += a1.x; a0.y += a1.y; a0.z += a1.z; a0.w += a1.w;
#pragma unroll
        for (int m = 16; m < 64; m <<= 1) {
            a0.x += __shfl_xor(a0.x, m, 64);
            a0.y += __shfl_xor(a0.y, m, 64);
            a0.z += __shfl_xor(a0.z, m, 64);
            a0.w += __shfl_xor(a0.w, m, 64);
        }
        float invd = 1.0f / fmaxf((float)(end - beg), 1.0f);
        if (t < 16)
            *(float4*)(&sA[w][t * 4]) =
                make_float4(a0.x * invd, a0.y * invd, a0.z * invd, a0.w * invd);
        sS[w][t] = h1[(size_t)node * HIDD + t];
    }
    __syncthreads();
    if (node >= N) return;
    float acc = b[t];
#pragma unroll 8
    for (int k = 0; k < HIDD; ++k)
        acc += sA[w][k] * sWl[k * HIDD + t] + sS[w][k] * sWr[k * HIDD + t];
    float val = fmaxf(acc, 0.0f);
    int g = batch[node];
    atomicAdd(pooled + (size_t)g * HIDD + t, val);
    if (t == 0) atomicAdd(cnt + g, 1.0f);
}

__global__ void final_k(const float* __restrict__ pooled, const float* __restrict__ cnt,
                        const float* __restrict__ W, const float* __restrict__ bl,
                        float* __restrict__ out, int G) {
    int g = blockIdx.x;
    if (g >= G) return;
    int t = threadIdx.x;
    float invc = 1.0f / fmaxf(cnt[g], 1.0f);
    float v = pooled[(size_t)g * HIDD + t] * invc * W[t];
#pragma unroll
    for (int o = 32; o > 0; o >>= 1) v += __shfl_down(v, o, 64);
    if (t == 0) out[g] = v + bl[0];
}

extern "C" void kernel_launch(void* const* d_in, const int* in_sizes, int n_in,
                              void* d_out, int out_size, void* d_ws, size_t ws_size,
                              hipStream_t stream) {
    const float* x   = (const float*)d_in[0];
    const float* pos = (const float*)d_in[1];
    const int* ei    = (const int*)d_in[2];
    const int* batch = (const int*)d_in[3];
    const float* W1l = (const float*)d_in[4];
    const float* W1r = (const float*)d_in[5];
    const float* b1  = (const float*)d_in[6];
    const float* W2l = (const float*)d_in[7];
    const float* W2r = (const float*)d_in[8];
    const float* b2  = (const float*)d_in[9];
    const float* Wl  = (const float*)d_in[10];
    const float* bl  = (const float*)d_in[11];
    float* out = (float*)d_out;

    int N = in_sizes[3];
    int E = in_sizes[2] / 2;
    int G = out_size;
    int NB = (N + RB - 1) >> 9;          // 196 for N=100000
    int chunk = (E + BH_BLOCKS - 1) / BH_BLOCKS;

    char* ws = (char*)d_ws;
    size_t off = 0;
    // ---- zero region (memset below) ----
    float* cnt = (float*)(ws + off);    off += (size_t)G * 4;
    float* pooled = (float*)(ws + off); off += (size_t)G * HIDD * 4;
    size_t zero_bytes = off;
    // ---- rest (all fully written each call before read) ----
    int* gcount = (int*)(ws + off);     off += (size_t)NB_MAX * BH_BLOCKS * 4;
    int* gbase  = (int*)(ws + off);     off += (size_t)NB_MAX * BH_BLOCKS * 4;
    int* btot   = (int*)(ws + off);     off += (size_t)NB_MAX * 4;
    int* bbase  = (int*)(ws + off);     off += (size_t)NB_MAX * 4;
    int* rowptr = (int*)(ws + off);     off += (size_t)(N + 1) * 4;
    off = (off + 255) & ~(size_t)255;
    int2* pairs = (int2*)(ws + off);    off += (size_t)E * 8;
    int* csr    = (int*)(ws + off);     off += (size_t)E * 4;
    off = (off + 255) & ~(size_t)255;
    float* h0p  = (float*)(ws + off);   off += (size_t)N * INDP * 4;
    off = (off + 255) & ~(size_t)255;
    float* h1   = (float*)(ws + off);   off += (size_t)N * HIDD * 4;

    hipMemsetAsync(d_ws, 0, zero_bytes, stream);

    int blk = 256;
    build_h0p<<<((size_t)N * INDP + blk - 1) / blk, blk, 0, stream>>>(x, pos, h0p, N);
    bhist<<<BH_BLOCKS, 256, 0, stream>>>(ei, gcount, E, NB, chunk);
    bscan1<<<(NB + 3) / 4, 256, 0, stream>>>(gcount, gbase, btot, NB);
    bscan2<<<1, 64, 0, stream>>>(btot, bbase, rowptr, NB, N, E);
    bscatter<<<BH_BLOCKS, 256, 0, stream>>>(ei, gbase, bbase, pairs, E, NB, chunk);
    csr_build<<<NB, 1024, 0, stream>>>(pairs, btot, bbase, rowptr, csr, N);
    agg_layer1<<<(N + 7) / 8, 512, 0, stream>>>(h0p, rowptr, csr, W1l, W1r, b1, h1, N);
    agg_layer2<<<(N + 7) / 8, 512, 0, stream>>>(h1, rowptr, csr, batch, W2l, W2r, b2,
                                                pooled, cnt, N);
    final_k<<<G, 64, 0, stream>>>(pooled, cnt, Wl, bl, out, G);
}

// Round 6
// 370.643 us; speedup vs baseline: 14.2967x; 1.0536x over previous
//
#include <hip/hip_runtime.h>

#define IND 14
#define INDP 16
#define HIDD 64
#define RB 512          // nodes per bucket (shift 9)
#define NB_MAX 256
#define BH_BLOCKS 512

typedef unsigned int uint;
typedef unsigned short ushort;

__device__ __forceinline__ float bf16lo(uint u) { return __uint_as_float(u << 16); }
__device__ __forceinline__ float bf16hi(uint u) { return __uint_as_float(u & 0xFFFF0000u); }
__device__ __forceinline__ ushort f2bf(float f) {
    uint u = __float_as_uint(f);
    u += 0x7FFFu + ((u >> 16) & 1u);   // round-to-nearest-even
    return (ushort)(u >> 16);
}

// h0p fp32 (padded 16) for self term; h0h bf16 rows (32B) for gathers
__global__ void build_h0p(const float* __restrict__ x, const float* __restrict__ pos,
                          float* __restrict__ h0p, ushort* __restrict__ h0h, int N) {
    int tid = blockIdx.x * blockDim.x + threadIdx.x;
    int total = N * INDP;
    if (tid >= total) return;
    int n = tid >> 4, d = tid & 15;
    float v = 0.0f;
    if (d < 11) v = x[n * 11 + d];
    else if (d < 14) v = pos[n * 3 + (d - 11)];
    h0p[tid] = v;
    h0h[tid] = f2bf(v);
}

__global__ __launch_bounds__(256) void bhist(const int* __restrict__ ei,
                                             int* __restrict__ gcount,
                                             int E, int NB, int chunk) {
    __shared__ int cntS[NB_MAX];
    cntS[threadIdx.x] = 0;
    __syncthreads();
    int start = blockIdx.x * chunk;
    int end = min(start + chunk, E);
    for (int e = start + threadIdx.x; e < end; e += 256)
        atomicAdd(&cntS[ei[E + e] >> 9], 1);
    __syncthreads();
    if (threadIdx.x < NB)
        gcount[(size_t)threadIdx.x * BH_BLOCKS + blockIdx.x] = cntS[threadIdx.x];
}

__global__ __launch_bounds__(256) void bscan1(const int* __restrict__ gcount,
                                              int* __restrict__ gbase,
                                              int* __restrict__ btot, int NB) {
    int wave = blockIdx.x * 4 + (threadIdx.x >> 6);
    int lane = threadIdx.x & 63;
    if (wave >= NB) return;
    const int* src = gcount + (size_t)wave * BH_BLOCKS;
    int* dstp = gbase + (size_t)wave * BH_BLOCKS;
    int run = 0;
#pragma unroll
    for (int r = 0; r < 8; ++r) {
        int val = src[r * 64 + lane];
        int inc = val;
#pragma unroll
        for (int off = 1; off < 64; off <<= 1) {
            int tv = __shfl_up(inc, off, 64);
            if (lane >= off) inc += tv;
        }
        dstp[r * 64 + lane] = run + inc - val;
        run += __shfl(inc, 63, 64);
    }
    if (lane == 0) btot[wave] = run;
}

__global__ void bscan2(const int* __restrict__ btot, int* __restrict__ bbase,
                       int* __restrict__ rowptr, int NB, int N, int E) {
    int lane = threadIdx.x;
    int run = 0;
#pragma unroll
    for (int r = 0; r < 4; ++r) {
        int i = r * 64 + lane;
        int val = (i < NB) ? btot[i] : 0;
        int inc = val;
#pragma unroll
        for (int off = 1; off < 64; off <<= 1) {
            int tv = __shfl_up(inc, off, 64);
            if (lane >= off) inc += tv;
        }
        if (i < NB) bbase[i] = run + inc - val;
        run += __shfl(inc, 63, 64);
    }
    if (lane == 0) rowptr[N] = E;
}

// C: scatter edges into bucket-contiguous packed words (local<<17 | src)
__global__ __launch_bounds__(256) void bscatter(const int* __restrict__ ei,
                                                const int* __restrict__ gbase,
                                                const int* __restrict__ bbase,
                                                uint* __restrict__ pairs,
                                                int E, int NB, int chunk) {
    __shared__ int cur[NB_MAX];
    if (threadIdx.x < NB)
        cur[threadIdx.x] = bbase[threadIdx.x] +
                           gbase[(size_t)threadIdx.x * BH_BLOCKS + blockIdx.x];
    __syncthreads();
    int start = blockIdx.x * chunk;
    int end = min(start + chunk, E);
    for (int e = start + threadIdx.x; e < end; e += 256) {
        int s = ei[e], d = ei[E + e];
        int p = atomicAdd(&cur[d >> 9], 1);
        pairs[p] = ((uint)(d & (RB - 1)) << 17) | (uint)s;
    }
}

__global__ __launch_bounds__(1024) void csr_build(const uint* __restrict__ pairs,
                                                  const int* __restrict__ btot,
                                                  const int* __restrict__ bbase,
                                                  int* __restrict__ rowptr,
                                                  int* __restrict__ csr, int N) {
    __shared__ int s[RB];
    __shared__ int fillS[RB];
    int b = blockIdx.x;
    int cnt = btot[b], base = bbase[b];
    int t = threadIdx.x;
    if (t < RB) { s[t] = 0; fillS[t] = 0; }
    __syncthreads();
    for (int i = t; i < cnt; i += 1024)
        atomicAdd(&s[pairs[base + i] >> 17], 1);
    __syncthreads();
    for (int off = 1; off < RB; off <<= 1) {
        int v = 0;
        if (t < RB && t >= off) v = s[t - off];
        __syncthreads();
        if (t < RB) s[t] += v;
        __syncthreads();
    }
    int node0 = b << 9;
    if (t < RB) {
        int node = node0 + t;
        if (node < N) rowptr[node] = base + (t ? s[t - 1] : 0);
    }
    __syncthreads();
    for (int i = t; i < cnt; i += 1024) {
        uint pk = pairs[base + i];
        int local = pk >> 17;
        int p = atomicAdd(&fillS[local], 1);
        int segbase = local ? s[local - 1] : 0;
        csr[base + segbase + p] = (int)(pk & 0x1FFFFu);
    }
}

// fused gather-mean(h0h bf16) + layer1 GEMM; wave per node, 8 nodes/block
__global__ __launch_bounds__(512) void agg_layer1(
        const float* __restrict__ h0p, const ushort* __restrict__ h0h,
        const int* __restrict__ rowptr, const int* __restrict__ csr,
        const float* __restrict__ W_l, const float* __restrict__ W_r,
        const float* __restrict__ b, float* __restrict__ h1f,
        ushort* __restrict__ h1h, int N) {
    __shared__ float sWl[IND * HIDD];
    __shared__ float sWr[IND * HIDD];
    __shared__ float sA[8][INDP];
    __shared__ float sS[8][INDP];
    for (int i = threadIdx.x; i < IND * HIDD; i += 512) {
        sWl[i] = W_l[i];
        sWr[i] = W_r[i];
    }
    int w = threadIdx.x >> 6, t = threadIdx.x & 63;
    int node = blockIdx.x * 8 + w;
    if (node < N) {
        int beg = rowptr[node], end = rowptr[node + 1];
        int s = t >> 1, hf = t & 1;  // 32 row-slots x 2 halves (8 bf16 = 16B each)
        float acc[8] = {0.f, 0.f, 0.f, 0.f, 0.f, 0.f, 0.f, 0.f};
        for (int e = beg + s; e < end; e += 32) {
            int idx = csr[e];
            const uint4 v = *(const uint4*)(h0h + (size_t)idx * INDP + hf * 8);
            acc[0] += bf16lo(v.x); acc[1] += bf16hi(v.x);
            acc[2] += bf16lo(v.y); acc[3] += bf16hi(v.y);
            acc[4] += bf16lo(v.z); acc[5] += bf16hi(v.z);
            acc[6] += bf16lo(v.w); acc[7] += bf16hi(v.w);
        }
#pragma unroll
        for (int m = 2; m < 64; m <<= 1) {
#pragma unroll
            for (int j = 0; j < 8; ++j) acc[j] += __shfl_xor(acc[j], m, 64);
        }
        float invd = 1.0f / fmaxf((float)(end - beg), 1.0f);
        if (t < 2) {
#pragma unroll
            for (int j = 0; j < 8; ++j) sA[w][t * 8 + j] = acc[j] * invd;
        }
        if (t < INDP) sS[w][t] = h0p[(size_t)node * INDP + t];
    }
    __syncthreads();
    if (node >= N) return;
    float acc = b[t];
#pragma unroll
    for (int k = 0; k < IND; ++k)
        acc += sA[w][k] * sWl[k * HIDD + t] + sS[w][k] * sWr[k * HIDD + t];
    float val = fmaxf(acc, 0.0f);
    h1f[(size_t)node * HIDD + t] = val;
    h1h[(size_t)node * HIDD + t] = f2bf(val);
}

// fused gather-mean(h1h bf16) + layer2 GEMM + pooled atomic; wave per node
__global__ __launch_bounds__(512) void agg_layer2(
        const float* __restrict__ h1f, const ushort* __restrict__ h1h,
        const int* __restrict__ rowptr, const int* __restrict__ csr,
        const int* __restrict__ batch,
        const float* __restrict__ W_l, const float* __restrict__ W_r,
        const float* __restrict__ b,
        float* __restrict__ pooled, float* __restrict__ cnt, int N) {
    __shared__ float sWl[HIDD * HIDD];
    __shared__ float sWr[HIDD * HIDD];
    __shared__ float sA[8][HIDD];
    __shared__ float sS[8][HIDD];
    for (int i = threadIdx.x; i < HIDD * HIDD; i += 512) {
        sWl[i] = W_l[i];
        sWr[i] = W_r[i];
    }
    int w = threadIdx.x >> 6, t = threadIdx.x & 63;
    int node = blockIdx.x * 8 + w;
    if (node < N) {
        int beg = rowptr[node], end = rowptr[node + 1];
        int s = t >> 3, p = t & 7;  // 8 row-slots x 8 parts (8 bf16 = 16B each)
        float a0[8] = {0.f, 0.f, 0.f, 0.f, 0.f, 0.f, 0.f, 0.f};
        float a1[8] = {0.f, 0.f, 0.f, 0.f, 0.f, 0.f, 0.f, 0.f};
        int e = beg + s;
        for (; e + 8 < end; e += 16) {  // 2 chains: 16 rows in flight per wave
            int i0 = csr[e];
            int i1 = csr[e + 8];
            const uint4 v0 = *(const uint4*)(h1h + (size_t)i0 * HIDD + p * 8);
            const uint4 v1 = *(const uint4*)(h1h + (size_t)i1 * HIDD + p * 8);
            a0[0] += bf16lo(v0.x); a0[1] += bf16hi(v0.x);
            a0[2] += bf16lo(v0.y); a0[3] += bf16hi(v0.y);
            a0[4] += bf16lo(v0.z); a0[5] += bf16hi(v0.z);
            a0[6] += bf16lo(v0.w); a0[7] += bf16hi(v0.w);
            a1[0] += bf16lo(v1.x); a1[1] += bf16hi(v1.x);
            a1[2] += bf16lo(v1.y); a1[3] += bf16hi(v1.y);
            a1[4] += bf16lo(v1.z); a1[5] += bf16hi(v1.z);
            a1[6] += bf16lo(v1.w); a1[7] += bf16hi(v1.w);
        }
        if (e < end) {
            int i0 = csr[e];
            const uint4 v0 = *(const uint4*)(h1h + (size_t)i0 * HIDD + p * 8);
            a0[0] += bf16lo(v0.x); a0[1] += bf16hi(v0.x);
            a0[2] += bf16lo(v0.y); a0[3] += bf16hi(v0.y);
            a0[4] += bf16lo(v0.z); a0[5] += bf16hi(v0.z);
            a0[6] += bf16lo(v0.w); a0[7] += bf16hi(v0.w);
        }
#pragma unroll
        for (int j = 0; j < 8; ++j) a0[j] += a1[j];
#pragma unroll
        for (int m = 8; m < 64; m <<= 1) {
#pragma unroll
            for (int j = 0; j < 8; ++j) a0[j] += __shfl_xor(a0[j], m, 64);
        }
        float invd = 1.0f / fmaxf((float)(end - beg), 1.0f);
        if (t < 8) {
#pragma unroll
            for (int j = 0; j < 8; ++j) sA[w][t * 8 + j] = a0[j] * invd;
        }
        sS[w][t] = h1f[(size_t)node * HIDD + t];
    }
    __syncthreads();
    if (node >= N) return;
    float acc = b[t];
#pragma unroll 8
    for (int k = 0; k < HIDD; ++k)
        acc += sA[w][k] * sWl[k * HIDD + t] + sS[w][k] * sWr[k * HIDD + t];
    float val = fmaxf(acc, 0.0f);
    int g = batch[node];
    atomicAdd(pooled + (size_t)g * HIDD + t, val);
    if (t == 0) atomicAdd(cnt + g, 1.0f);
}

__global__ void final_k(const float* __restrict__ pooled, const float* __restrict__ cnt,
                        const float* __restrict__ W, const float* __restrict__ bl,
                        float* __restrict__ out, int G) {
    int g = blockIdx.x;
    if (g >= G) return;
    int t = threadIdx.x;
    float invc = 1.0f / fmaxf(cnt[g], 1.0f);
    float v = pooled[(size_t)g * HIDD + t] * invc * W[t];
#pragma unroll
    for (int o = 32; o > 0; o >>= 1) v += __shfl_down(v, o, 64);
    if (t == 0) out[g] = v + bl[0];
}

extern "C" void kernel_launch(void* const* d_in, const int* in_sizes, int n_in,
                              void* d_out, int out_size, void* d_ws, size_t ws_size,
                              hipStream_t stream) {
    const float* x   = (const float*)d_in[0];
    const float* pos = (const float*)d_in[1];
    const int* ei    = (const int*)d_in[2];
    const int* batch = (const int*)d_in[3];
    const float* W1l = (const float*)d_in[4];
    const float* W1r = (const float*)d_in[5];
    const float* b1  = (const float*)d_in[6];
    const float* W2l = (const float*)d_in[7];
    const float* W2r = (const float*)d_in[8];
    const float* b2  = (const float*)d_in[9];
    const float* Wl  = (const float*)d_in[10];
    const float* bl  = (const float*)d_in[11];
    float* out = (float*)d_out;

    int N = in_sizes[3];
    int E = in_sizes[2] / 2;
    int G = out_size;
    int NB = (N + RB - 1) >> 9;
    int chunk = (E + BH_BLOCKS - 1) / BH_BLOCKS;

    char* ws = (char*)d_ws;
    size_t off = 0;
    // ---- zero region (memset below) ----
    float* cnt = (float*)(ws + off);    off += (size_t)G * 4;
    float* pooled = (float*)(ws + off); off += (size_t)G * HIDD * 4;
    size_t zero_bytes = off;
    // ---- rest (fully written before read each call) ----
    int* gcount = (int*)(ws + off);     off += (size_t)NB_MAX * BH_BLOCKS * 4;
    int* gbase  = (int*)(ws + off);     off += (size_t)NB_MAX * BH_BLOCKS * 4;
    int* btot   = (int*)(ws + off);     off += (size_t)NB_MAX * 4;
    int* bbase  = (int*)(ws + off);     off += (size_t)NB_MAX * 4;
    int* rowptr = (int*)(ws + off);     off += (size_t)(N + 1) * 4;
    off = (off + 255) & ~(size_t)255;
    uint* pairs = (uint*)(ws + off);    off += (size_t)E * 4;
    int* csr    = (int*)(ws + off);     off += (size_t)E * 4;
    off = (off + 255) & ~(size_t)255;
    float* h0p  = (float*)(ws + off);   off += (size_t)N * INDP * 4;
    off = (off + 255) & ~(size_t)255;
    ushort* h0h = (ushort*)(ws + off);  off += (size_t)N * INDP * 2;
    off = (off + 255) & ~(size_t)255;
    float* h1f  = (float*)(ws + off);   off += (size_t)N * HIDD * 4;
    off = (off + 255) & ~(size_t)255;
    ushort* h1h = (ushort*)(ws + off);  off += (size_t)N * HIDD * 2;

    hipMemsetAsync(d_ws, 0, zero_bytes, stream);

    int blk = 256;
    build_h0p<<<((size_t)N * INDP + blk - 1) / blk, blk, 0, stream>>>(x, pos, h0p, h0h, N);
    bhist<<<BH_BLOCKS, 256, 0, stream>>>(ei, gcount, E, NB, chunk);
    bscan1<<<(NB + 3) / 4, 256, 0, stream>>>(gcount, gbase, btot, NB);
    bscan2<<<1, 64, 0, stream>>>(btot, bbase, rowptr, NB, N, E);
    bscatter<<<BH_BLOCKS, 256, 0, stream>>>(ei, gbase, bbase, pairs, E, NB, chunk);
    csr_build<<<NB, 1024, 0, stream>>>(pairs, btot, bbase, rowptr, csr, N);
    agg_layer1<<<(N + 7) / 8, 512, 0, stream>>>(h0p, h0h, rowptr, csr, W1l, W1r, b1,
                                                h1f, h1h, N);
    agg_layer2<<<(N + 7) / 8, 512, 0, stream>>>(h1f, h1h, rowptr, csr, batch,
                                                W2l, W2r, b2, pooled, cnt, N);
    final_k<<<G, 64, 0, stream>>>(pooled, cnt, Wl, bl, out, G);
}

// Round 7
// 364.955 us; speedup vs baseline: 14.5195x; 1.0156x over previous
//
#include <hip/hip_runtime.h>

#define IND 14
#define INDP 16
#define HIDD 64
#define RB 512          // nodes per bucket (shift 9)
#define NB_MAX 256
#define BH_BLOCKS 512
#define CAP 18432       // per-bucket pairs/csr capacity (mean 16384, sigma 128)

typedef unsigned int uint;
typedef unsigned short ushort;

__device__ __forceinline__ float bf16lo(uint u) { return __uint_as_float(u << 16); }
__device__ __forceinline__ float bf16hi(uint u) { return __uint_as_float(u & 0xFFFF0000u); }
__device__ __forceinline__ ushort f2bf(float f) {
    uint u = __float_as_uint(f);
    u += 0x7FFFu + ((u >> 16) & 1u);   // round-to-nearest-even
    return (ushort)(u >> 16);
}

__global__ void build_h0p(const float* __restrict__ x, const float* __restrict__ pos,
                          float* __restrict__ h0p, ushort* __restrict__ h0h, int N) {
    int tid = blockIdx.x * blockDim.x + threadIdx.x;
    int total = N * INDP;
    if (tid >= total) return;
    int n = tid >> 4, d = tid & 15;
    float v = 0.0f;
    if (d < 11) v = x[n * 11 + d];
    else if (d < 14) v = pos[n * 3 + (d - 11)];
    h0p[tid] = v;
    h0h[tid] = f2bf(v);
}

// fused single-pass bucket scatter: LDS count -> reserve range -> LDS-cursor scatter
__global__ __launch_bounds__(256) void bscat_fused(const int* __restrict__ ei,
                                                   int* __restrict__ gcur,
                                                   uint* __restrict__ pairs,
                                                   int E, int NB, int chunk) {
    __shared__ int cntS[NB_MAX];
    __shared__ int baseS[NB_MAX];
    cntS[threadIdx.x] = 0;
    __syncthreads();
    int start = blockIdx.x * chunk;
    int end = min(start + chunk, E);
    for (int e = start + threadIdx.x; e < end; e += 256)
        atomicAdd(&cntS[ei[E + e] >> 9], 1);
    __syncthreads();
    if (threadIdx.x < NB) {
        int c = cntS[threadIdx.x];
        baseS[threadIdx.x] = c ? atomicAdd(&gcur[threadIdx.x], c) : 0;
        cntS[threadIdx.x] = 0;   // reuse as local cursor
    }
    __syncthreads();
    for (int e = start + threadIdx.x; e < end; e += 256) {
        int s = ei[e], d = ei[E + e];
        int b = d >> 9;
        int p = atomicAdd(&cntS[b], 1) + baseS[b];
        pairs[(size_t)b * CAP + p] = ((uint)(d & (RB - 1)) << 17) | (uint)s;
    }
}

// block per bucket: LDS deg hist + scan -> rowseg(int2) + bucket-padded csr
__global__ __launch_bounds__(1024) void csr_build(const uint* __restrict__ pairs,
                                                  const int* __restrict__ gcur,
                                                  int2* __restrict__ rowseg,
                                                  int* __restrict__ csr, int N) {
    __shared__ int s[RB];
    __shared__ int fillS[RB];
    int b = blockIdx.x;
    int cnt = gcur[b];
    size_t base = (size_t)b * CAP;
    int t = threadIdx.x;
    if (t < RB) { s[t] = 0; fillS[t] = 0; }
    __syncthreads();
    for (int i = t; i < cnt; i += 1024)
        atomicAdd(&s[pairs[base + i] >> 17], 1);
    __syncthreads();
    for (int off = 1; off < RB; off <<= 1) {
        int v = 0;
        if (t < RB && t >= off) v = s[t - off];
        __syncthreads();
        if (t < RB) s[t] += v;
        __syncthreads();
    }
    int node0 = b << 9;
    if (t < RB) {
        int node = node0 + t;
        if (node < N)
            rowseg[node] = make_int2((int)base + (t ? s[t - 1] : 0), (int)base + s[t]);
    }
    __syncthreads();
    for (int i = t; i < cnt; i += 1024) {
        uint pk = pairs[base + i];
        int local = pk >> 17;
        int p = atomicAdd(&fillS[local], 1);
        int segbase = local ? s[local - 1] : 0;
        csr[base + segbase + p] = (int)(pk & 0x1FFFFu);
    }
}

// fused gather-mean(h0h) + layer1; wave/node, 32 slots x 2 halves, 2 chains (64 edges/iter)
__global__ __launch_bounds__(512) void agg_layer1(
        const float* __restrict__ h0p, const ushort* __restrict__ h0h,
        const int2* __restrict__ rowseg, const int* __restrict__ csr,
        const float* __restrict__ W_l, const float* __restrict__ W_r,
        const float* __restrict__ b, float* __restrict__ h1f,
        ushort* __restrict__ h1h, int N) {
    __shared__ float sWl[IND * HIDD];
    __shared__ float sWr[IND * HIDD];
    __shared__ float sA[8][INDP];
    __shared__ float sS[8][INDP];
    for (int i = threadIdx.x; i < IND * HIDD; i += 512) {
        sWl[i] = W_l[i];
        sWr[i] = W_r[i];
    }
    int w = threadIdx.x >> 6, t = threadIdx.x & 63;
    int node = blockIdx.x * 8 + w;
    if (node < N) {
        int2 seg = rowseg[node];
        int beg = seg.x, end = seg.y;
        int s = t >> 1, hf = t & 1;
        float acc[8] = {0.f, 0.f, 0.f, 0.f, 0.f, 0.f, 0.f, 0.f};
        for (int cb = beg; cb < end; cb += 64) {
            int e0 = cb + s, e1 = e0 + 32;
            int i0 = csr[min(e0, end - 1)];
            int i1 = csr[min(e1, end - 1)];
            float m0 = (e0 < end) ? 1.f : 0.f;
            float m1 = (e1 < end) ? 1.f : 0.f;
            const uint4 v0 = *(const uint4*)(h0h + (size_t)i0 * INDP + hf * 8);
            const uint4 v1 = *(const uint4*)(h0h + (size_t)i1 * INDP + hf * 8);
            acc[0] = fmaf(m0, bf16lo(v0.x), acc[0]); acc[1] = fmaf(m0, bf16hi(v0.x), acc[1]);
            acc[2] = fmaf(m0, bf16lo(v0.y), acc[2]); acc[3] = fmaf(m0, bf16hi(v0.y), acc[3]);
            acc[4] = fmaf(m0, bf16lo(v0.z), acc[4]); acc[5] = fmaf(m0, bf16hi(v0.z), acc[5]);
            acc[6] = fmaf(m0, bf16lo(v0.w), acc[6]); acc[7] = fmaf(m0, bf16hi(v0.w), acc[7]);
            acc[0] = fmaf(m1, bf16lo(v1.x), acc[0]); acc[1] = fmaf(m1, bf16hi(v1.x), acc[1]);
            acc[2] = fmaf(m1, bf16lo(v1.y), acc[2]); acc[3] = fmaf(m1, bf16hi(v1.y), acc[3]);
            acc[4] = fmaf(m1, bf16lo(v1.z), acc[4]); acc[5] = fmaf(m1, bf16hi(v1.z), acc[5]);
            acc[6] = fmaf(m1, bf16lo(v1.w), acc[6]); acc[7] = fmaf(m1, bf16hi(v1.w), acc[7]);
        }
#pragma unroll
        for (int m = 2; m < 64; m <<= 1) {
#pragma unroll
            for (int j = 0; j < 8; ++j) acc[j] += __shfl_xor(acc[j], m, 64);
        }
        float invd = 1.0f / fmaxf((float)(end - beg), 1.0f);
        if (t < 2) {
#pragma unroll
            for (int j = 0; j < 8; ++j) sA[w][t * 8 + j] = acc[j] * invd;
        }
        if (t < INDP) sS[w][t] = h0p[(size_t)node * INDP + t];
    }
    __syncthreads();
    if (node >= N) return;
    float acc = b[t];
#pragma unroll
    for (int k = 0; k < IND; ++k)
        acc += sA[w][k] * sWl[k * HIDD + t] + sS[w][k] * sWr[k * HIDD + t];
    float val = fmaxf(acc, 0.0f);
    h1f[(size_t)node * HIDD + t] = val;
    h1h[(size_t)node * HIDD + t] = f2bf(val);
}

// fused gather-mean(h1h) + layer2 + pooled atomic; wave/node, 8 slots x 8 parts, 4 chains
__global__ __launch_bounds__(512) void agg_layer2(
        const float* __restrict__ h1f, const ushort* __restrict__ h1h,
        const int2* __restrict__ rowseg, const int* __restrict__ csr,
        const int* __restrict__ batch,
        const float* __restrict__ W_l, const float* __restrict__ W_r,
        const float* __restrict__ b,
        float* __restrict__ pooled, float* __restrict__ cnt, int N) {
    __shared__ float sWl[HIDD * HIDD];
    __shared__ float sWr[HIDD * HIDD];
    __shared__ float sA[8][HIDD];
    __shared__ float sS[8][HIDD];
    for (int i = threadIdx.x; i < HIDD * HIDD; i += 512) {
        sWl[i] = W_l[i];
        sWr[i] = W_r[i];
    }
    int w = threadIdx.x >> 6, t = threadIdx.x & 63;
    int node = blockIdx.x * 8 + w;
    if (node < N) {
        int2 seg = rowseg[node];
        int beg = seg.x, end = seg.y;
        int s = t >> 3, p = t & 7;
        float acc[8] = {0.f, 0.f, 0.f, 0.f, 0.f, 0.f, 0.f, 0.f};
        for (int cb = beg; cb < end; cb += 32) {
            int e0 = cb + s, e1 = e0 + 8, e2 = e0 + 16, e3 = e0 + 24;
            int i0 = csr[min(e0, end - 1)];
            int i1 = csr[min(e1, end - 1)];
            int i2 = csr[min(e2, end - 1)];
            int i3 = csr[min(e3, end - 1)];
            float m0 = (e0 < end) ? 1.f : 0.f;
            float m1 = (e1 < end) ? 1.f : 0.f;
            float m2 = (e2 < end) ? 1.f : 0.f;
            float m3 = (e3 < end) ? 1.f : 0.f;
            const uint4 v0 = *(const uint4*)(h1h + (size_t)i0 * HIDD + p * 8);
            const uint4 v1 = *(const uint4*)(h1h + (size_t)i1 * HIDD + p * 8);
            const uint4 v2 = *(const uint4*)(h1h + (size_t)i2 * HIDD + p * 8);
            const uint4 v3 = *(const uint4*)(h1h + (size_t)i3 * HIDD + p * 8);
            acc[0] = fmaf(m0, bf16lo(v0.x), acc[0]); acc[1] = fmaf(m0, bf16hi(v0.x), acc[1]);
            acc[2] = fmaf(m0, bf16lo(v0.y), acc[2]); acc[3] = fmaf(m0, bf16hi(v0.y), acc[3]);
            acc[4] = fmaf(m0, bf16lo(v0.z), acc[4]); acc[5] = fmaf(m0, bf16hi(v0.z), acc[5]);
            acc[6] = fmaf(m0, bf16lo(v0.w), acc[6]); acc[7] = fmaf(m0, bf16hi(v0.w), acc[7]);
            acc[0] = fmaf(m1, bf16lo(v1.x), acc[0]); acc[1] = fmaf(m1, bf16hi(v1.x), acc[1]);
            acc[2] = fmaf(m1, bf16lo(v1.y), acc[2]); acc[3] = fmaf(m1, bf16hi(v1.y), acc[3]);
            acc[4] = fmaf(m1, bf16lo(v1.z), acc[4]); acc[5] = fmaf(m1, bf16hi(v1.z), acc[5]);
            acc[6] = fmaf(m1, bf16lo(v1.w), acc[6]); acc[7] = fmaf(m1, bf16hi(v1.w), acc[7]);
            acc[0] = fmaf(m2, bf16lo(v2.x), acc[0]); acc[1] = fmaf(m2, bf16hi(v2.x), acc[1]);
            acc[2] = fmaf(m2, bf16lo(v2.y), acc[2]); acc[3] = fmaf(m2, bf16hi(v2.y), acc[3]);
            acc[4] = fmaf(m2, bf16lo(v2.z), acc[4]); acc[5] = fmaf(m2, bf16hi(v2.z), acc[5]);
            acc[6] = fmaf(m2, bf16lo(v2.w), acc[6]); acc[7] = fmaf(m2, bf16hi(v2.w), acc[7]);
            acc[0] = fmaf(m3, bf16lo(v3.x), acc[0]); acc[1] = fmaf(m3, bf16hi(v3.x), acc[1]);
            acc[2] = fmaf(m3, bf16lo(v3.y), acc[2]); acc[3] = fmaf(m3, bf16hi(v3.y), acc[3]);
            acc[4] = fmaf(m3, bf16lo(v3.z), acc[4]); acc[5] = fmaf(m3, bf16hi(v3.z), acc[5]);
            acc[6] = fmaf(m3, bf16lo(v3.w), acc[6]); acc[7] = fmaf(m3, bf16hi(v3.w), acc[7]);
        }
#pragma unroll
        for (int m = 8; m < 64; m <<= 1) {
#pragma unroll
            for (int j = 0; j < 8; ++j) acc[j] += __shfl_xor(acc[j], m, 64);
        }
        float invd = 1.0f / fmaxf((float)(end - beg), 1.0f);
        if (t < 8) {
#pragma unroll
            for (int j = 0; j < 8; ++j) sA[w][t * 8 + j] = acc[j] * invd;
        }
        sS[w][t] = h1f[(size_t)node * HIDD + t];
    }
    __syncthreads();
    if (node >= N) return;
    float acc = b[t];
#pragma unroll 8
    for (int k = 0; k < HIDD; ++k)
        acc += sA[w][k] * sWl[k * HIDD + t] + sS[w][k] * sWr[k * HIDD + t];
    float val = fmaxf(acc, 0.0f);
    int g = batch[node];
    atomicAdd(pooled + (size_t)g * HIDD + t, val);
    if (t == 0) atomicAdd(cnt + g, 1.0f);
}

__global__ void final_k(const float* __restrict__ pooled, const float* __restrict__ cnt,
                        const float* __restrict__ W, const float* __restrict__ bl,
                        float* __restrict__ out, int G) {
    int g = blockIdx.x;
    if (g >= G) return;
    int t = threadIdx.x;
    float invc = 1.0f / fmaxf(cnt[g], 1.0f);
    float v = pooled[(size_t)g * HIDD + t] * invc * W[t];
#pragma unroll
    for (int o = 32; o > 0; o >>= 1) v += __shfl_down(v, o, 64);
    if (t == 0) out[g] = v + bl[0];
}

extern "C" void kernel_launch(void* const* d_in, const int* in_sizes, int n_in,
                              void* d_out, int out_size, void* d_ws, size_t ws_size,
                              hipStream_t stream) {
    const float* x   = (const float*)d_in[0];
    const float* pos = (const float*)d_in[1];
    const int* ei    = (const int*)d_in[2];
    const int* batch = (const int*)d_in[3];
    const float* W1l = (const float*)d_in[4];
    const float* W1r = (const float*)d_in[5];
    const float* b1  = (const float*)d_in[6];
    const float* W2l = (const float*)d_in[7];
    const float* W2r = (const float*)d_in[8];
    const float* b2  = (const float*)d_in[9];
    const float* Wl  = (const float*)d_in[10];
    const float* bl  = (const float*)d_in[11];
    float* out = (float*)d_out;

    int N = in_sizes[3];
    int E = in_sizes[2] / 2;
    int G = out_size;
    int NB = (N + RB - 1) >> 9;
    int chunk = (E + BH_BLOCKS - 1) / BH_BLOCKS;

    char* ws = (char*)d_ws;
    size_t off = 0;
    // ---- zero region (memset below) ----
    float* cnt = (float*)(ws + off);    off += (size_t)G * 4;
    float* pooled = (float*)(ws + off); off += (size_t)G * HIDD * 4;
    int* gcur = (int*)(ws + off);       off += (size_t)NB_MAX * 4;
    size_t zero_bytes = off;
    // ---- rest (fully written before read each call) ----
    off = (off + 255) & ~(size_t)255;
    int2* rowseg = (int2*)(ws + off);   off += (size_t)N * 8;
    uint* pairs = (uint*)(ws + off);    off += (size_t)NB * CAP * 4;
    int* csr    = (int*)(ws + off);     off += (size_t)NB * CAP * 4;
    off = (off + 255) & ~(size_t)255;
    float* h0p  = (float*)(ws + off);   off += (size_t)N * INDP * 4;
    off = (off + 255) & ~(size_t)255;
    ushort* h0h = (ushort*)(ws + off);  off += (size_t)N * INDP * 2;
    off = (off + 255) & ~(size_t)255;
    float* h1f  = (float*)(ws + off);   off += (size_t)N * HIDD * 4;
    off = (off + 255) & ~(size_t)255;
    ushort* h1h = (ushort*)(ws + off);  off += (size_t)N * HIDD * 2;

    hipMemsetAsync(d_ws, 0, zero_bytes, stream);

    int blk = 256;
    build_h0p<<<((size_t)N * INDP + blk - 1) / blk, blk, 0, stream>>>(x, pos, h0p, h0h, N);
    bscat_fused<<<BH_BLOCKS, 256, 0, stream>>>(ei, gcur, pairs, E, NB, chunk);
    csr_build<<<NB, 1024, 0, stream>>>(pairs, gcur, rowseg, csr, N);
    agg_layer1<<<(N + 7) / 8, 512, 0, stream>>>(h0p, h0h, rowseg, csr, W1l, W1r, b1,
                                                h1f, h1h, N);
    agg_layer2<<<(N + 7) / 8, 512, 0, stream>>>(h1f, h1h, rowseg, csr, batch,
                                                W2l, W2r, b2, pooled, cnt, N);
    final_k<<<G, 64, 0, stream>>>(pooled, cnt, Wl, bl, out, G);
}